// Round 1
// baseline (532.867 us; speedup 1.0000x reference)
//
#include <hip/hip_runtime.h>
#include <stdint.h>

#define BB 4
#define TT 2048
#define CC 1024
#define HH 16
#define DD 64
#define MM (BB*TT)

typedef unsigned short u16;
typedef unsigned int   u32;
typedef __attribute__((ext_vector_type(8))) __bf16 bf16x8;
typedef __attribute__((ext_vector_type(4))) float  f32x4;

typedef __attribute__((address_space(1))) const u32 as1_u32;
typedef __attribute__((address_space(3))) u32       as3_u32;

// f32 -> bf16 round-to-nearest-even
__device__ __forceinline__ u16 f2b(float f) {
    u32 u = __builtin_bit_cast(u32, f);
    u32 r = u + 0x7FFFu + ((u >> 16) & 1u);
    return (u16)(r >> 16);
}

__device__ __forceinline__ f32x4 mfma16(uint4 a, uint4 b, f32x4 c) {
    return __builtin_amdgcn_mfma_f32_16x16x32_bf16(
        __builtin_bit_cast(bf16x8, a), __builtin_bit_cast(bf16x8, b), c, 0, 0, 0);
}

__device__ __forceinline__ void glds16(const u16* g, u16* l) {
    __builtin_amdgcn_global_load_lds((const as1_u32*)g, (as3_u32*)l, 16, 0, 0);
}

// ---------------- f32 -> bf16 convert ----------------
__global__ __launch_bounds__(256) void cvt_kernel(const float* __restrict__ s,
                                                  u16* __restrict__ d, int n) {
    int i = (blockIdx.x * 256 + threadIdx.x) * 4;
    if (i < n) {
        float4 v = *(const float4*)(s + i);
        ushort4 o;
        o.x = f2b(v.x); o.y = f2b(v.y); o.z = f2b(v.z); o.w = f2b(v.w);
        *(ushort4*)(d + i) = o;
    }
}

// ---------------- GEMM: Out[m,n] = sum_k A[m,k]*Bw[n,k]  (both K-contiguous bf16) ----
// MODE 0: bf16 row-major [M,N] out
// MODE 1: bf16 per-head transposed out: Out[((b*H+h)*64+d)*T + t], n = h*64+d, m = b*T+t
// MODE 2: f32 out + bias
template<int MODE>
__global__ __launch_bounds__(256, 2)
void gemm_bt(const u16* __restrict__ A, const u16* __restrict__ Bw,
             const float* __restrict__ bias, void* __restrict__ Out) {
    __shared__ u16 As[128 * 32];
    __shared__ u16 Bs[128 * 32];

    const int tid  = threadIdx.x;
    const int lane = tid & 63;
    const int wv   = tid >> 6;
    const int m0   = blockIdx.x * 128;
    const int n0   = blockIdx.y * 128;
    const int wm   = (wv & 1) * 64;
    const int wn   = (wv >> 1) * 64;
    const int fr   = lane & 15;
    const int fg   = lane >> 4;

    // staging: 8 chunks of 1KB per 8KB tile; wave w does chunks w and w+4
    const int srow = wv * 16 + (lane >> 2);   // row handled by this lane (chunk wv)
    const int sel  = (lane & 3) * 8;          // element offset within 32-el row

    const u16* gA0 = A  + (size_t)(m0 + srow) * CC + sel;
    const u16* gA1 = gA0 + (size_t)64 * CC;
    const u16* gB0 = Bw + (size_t)(n0 + srow) * CC + sel;
    const u16* gB1 = gB0 + (size_t)64 * CC;
    u16* sA0 = As + wv * 512;
    u16* sA1 = As + 2048 + wv * 512;
    u16* sB0 = Bs + wv * 512;
    u16* sB1 = Bs + 2048 + wv * 512;

    f32x4 acc[4][4] = {};

    for (int k0 = 0; k0 < CC; k0 += 32) {
        glds16(gA0 + k0, sA0);
        glds16(gA1 + k0, sA1);
        glds16(gB0 + k0, sB0);
        glds16(gB1 + k0, sB1);
        __syncthreads();
        uint4 af[4], bfr[4];
#pragma unroll
        for (int i = 0; i < 4; ++i)
            af[i] = *(const uint4*)(As + (wm + i * 16 + fr) * 32 + fg * 8);
#pragma unroll
        for (int i = 0; i < 4; ++i)
            bfr[i] = *(const uint4*)(Bs + (wn + i * 16 + fr) * 32 + fg * 8);
#pragma unroll
        for (int mi = 0; mi < 4; ++mi)
#pragma unroll
            for (int ni = 0; ni < 4; ++ni)
                acc[mi][ni] = mfma16(af[mi], bfr[ni], acc[mi][ni]);
        __syncthreads();
    }

    if constexpr (MODE == 0) {
        u16* O = (u16*)Out;
#pragma unroll
        for (int mi = 0; mi < 4; ++mi)
#pragma unroll
            for (int r = 0; r < 4; ++r) {
                int m = m0 + wm + mi * 16 + fg * 4 + r;
                size_t base = (size_t)m * CC + n0 + wn + fr;
#pragma unroll
                for (int ni = 0; ni < 4; ++ni)
                    O[base + ni * 16] = f2b(acc[mi][ni][r]);
            }
    } else if constexpr (MODE == 1) {
        u16* O = (u16*)Out;
#pragma unroll
        for (int mi = 0; mi < 4; ++mi) {
            int m = m0 + wm + mi * 16 + fg * 4;   // r=0 row; 4 consecutive t
            int b = m >> 11, t = m & 2047;
#pragma unroll
            for (int ni = 0; ni < 4; ++ni) {
                int n = n0 + wn + ni * 16 + fr;   // = h*64 + d
                ushort4 o;
                o.x = f2b(acc[mi][ni][0]); o.y = f2b(acc[mi][ni][1]);
                o.z = f2b(acc[mi][ni][2]); o.w = f2b(acc[mi][ni][3]);
                *(ushort4*)(O + ((size_t)b * CC + n) * TT + t) = o;
            }
        }
    } else {
        float* O = (float*)Out;
#pragma unroll
        for (int mi = 0; mi < 4; ++mi)
#pragma unroll
            for (int r = 0; r < 4; ++r) {
                int m = m0 + wm + mi * 16 + fg * 4 + r;
                size_t base = (size_t)m * CC + n0 + wn + fr;
#pragma unroll
                for (int ni = 0; ni < 4; ++ni)
                    O[base + ni * 16] = acc[mi][ni][r] + bias[n0 + wn + ni * 16 + fr];
            }
    }
}

// ---------------- flash attention ----------------
// Qp,Kp: bf16 [B,T,C] (head-interleaved); Vt: bf16 [B*H*64, T]; Att out: bf16 [B,T,C]
__global__ __launch_bounds__(256, 2)
void flash_attn(const u16* __restrict__ Qp, const u16* __restrict__ Kp,
                const u16* __restrict__ Vt, u16* __restrict__ Att) {
    __shared__ u16 Qs[128 * 72];
    __shared__ u16 Ks[64 * 72];
    __shared__ u16 Vs[64 * 72];
    __shared__ u16 Ps[4 * 32 * 72];

    const int tid = threadIdx.x, lane = tid & 63, wv = tid >> 6;
    const int fr = lane & 15, fg = lane >> 4;
    const int qi = blockIdx.x, bh = blockIdx.y;
    const int b = bh >> 4, h = bh & 15;
    const int q0 = qi * 128;

    // stage Q tile [128][64] -> Qs[128][72]
#pragma unroll
    for (int i = 0; i < 4; ++i) {
        int ch = i * 256 + tid;
        int r = ch >> 3, cp = (ch & 7) * 8;
        *(uint4*)(Qs + r * 72 + cp) =
            *(const uint4*)(Qp + ((size_t)(b * TT + q0 + r)) * CC + h * 64 + cp);
    }
    __syncthreads();

    uint4 qf[2][2];
#pragma unroll
    for (int mi = 0; mi < 2; ++mi)
#pragma unroll
        for (int ks = 0; ks < 2; ++ks)
            qf[mi][ks] = *(const uint4*)(Qs + (wv * 32 + mi * 16 + fr) * 72 + ks * 32 + fg * 8);

    f32x4 oacc[2][4] = {};
    float mst[2][4], lst[2][4];
#pragma unroll
    for (int mi = 0; mi < 2; ++mi)
#pragma unroll
        for (int r = 0; r < 4; ++r) { mst[mi][r] = -1e30f; lst[mi][r] = 0.f; }

    u16* pw = Ps + wv * 32 * 72;
    const float csc = 0.5f * 1.44269504088896f;  // (1/sqrt(B)) * log2(e)
    const int nkt = 2 * (qi + 1);

    for (int kt = 0; kt < nkt; ++kt) {
        const int k0 = kt * 64;
        // stage K tile [64][64] and V^T tile [64 d][64 t]
#pragma unroll
        for (int i = 0; i < 2; ++i) {
            int ch = i * 256 + tid;
            int r = ch >> 3, cp = (ch & 7) * 8;
            *(uint4*)(Ks + r * 72 + cp) =
                *(const uint4*)(Kp + ((size_t)(b * TT + k0 + r)) * CC + h * 64 + cp);
            *(uint4*)(Vs + r * 72 + cp) =
                *(const uint4*)(Vt + ((size_t)(bh * 64 + r)) * TT + k0 + cp);
        }
        __syncthreads();

        // S = Q K^T  (per wave: 32 q-rows x 64 k-cols)
        uint4 kf[4][2];
#pragma unroll
        for (int ni = 0; ni < 4; ++ni)
#pragma unroll
            for (int ks = 0; ks < 2; ++ks)
                kf[ni][ks] = *(const uint4*)(Ks + (ni * 16 + fr) * 72 + ks * 32 + fg * 8);
        f32x4 s[2][4];
#pragma unroll
        for (int mi = 0; mi < 2; ++mi)
#pragma unroll
            for (int ni = 0; ni < 4; ++ni) {
                f32x4 a = {0.f, 0.f, 0.f, 0.f};
                a = mfma16(qf[mi][0], kf[ni][0], a);
                a = mfma16(qf[mi][1], kf[ni][1], a);
                s[mi][ni] = a;
            }

        // scale (exp2 domain) + causal mask
        const bool needmask = (k0 + 63 > q0 + wv * 32);
#pragma unroll
        for (int mi = 0; mi < 2; ++mi)
#pragma unroll
            for (int ni = 0; ni < 4; ++ni)
#pragma unroll
                for (int r = 0; r < 4; ++r) {
                    float sv = s[mi][ni][r] * csc;
                    if (needmask) {
                        int tq = q0 + wv * 32 + mi * 16 + fg * 4 + r;
                        int tk = k0 + ni * 16 + fr;
                        sv = (tk > tq) ? -1e30f : sv;
                    }
                    s[mi][ni][r] = sv;
                }

        // online softmax (row = fg*4+r within 16-tile; 16 lanes of a fg-group share a row)
#pragma unroll
        for (int mi = 0; mi < 2; ++mi)
#pragma unroll
            for (int r = 0; r < 4; ++r) {
                float mx = fmaxf(fmaxf(s[mi][0][r], s[mi][1][r]),
                                 fmaxf(s[mi][2][r], s[mi][3][r]));
                mx = fmaxf(mx, __shfl_xor(mx, 1));
                mx = fmaxf(mx, __shfl_xor(mx, 2));
                mx = fmaxf(mx, __shfl_xor(mx, 4));
                mx = fmaxf(mx, __shfl_xor(mx, 8));
                float mnew = fmaxf(mst[mi][r], mx);
                float alpha = exp2f(mst[mi][r] - mnew);
                mst[mi][r] = mnew;
                float rs = 0.f;
#pragma unroll
                for (int ni = 0; ni < 4; ++ni) {
                    float p = exp2f(s[mi][ni][r] - mnew);
                    s[mi][ni][r] = p;
                    rs += p;
                }
                rs += __shfl_xor(rs, 1);
                rs += __shfl_xor(rs, 2);
                rs += __shfl_xor(rs, 4);
                rs += __shfl_xor(rs, 8);
                lst[mi][r] = lst[mi][r] * alpha + rs;
#pragma unroll
                for (int ni = 0; ni < 4; ++ni) oacc[mi][ni][r] *= alpha;
            }

        // P: C/D layout -> LDS -> A layout (per-wave private region, in-order DS pipe)
#pragma unroll
        for (int mi = 0; mi < 2; ++mi)
#pragma unroll
            for (int ni = 0; ni < 4; ++ni)
#pragma unroll
                for (int r = 0; r < 4; ++r)
                    pw[(mi * 16 + fg * 4 + r) * 72 + ni * 16 + fr] = f2b(s[mi][ni][r]);

        // O += P V
        uint4 vf[4][2];
#pragma unroll
        for (int ni = 0; ni < 4; ++ni)
#pragma unroll
            for (int ks = 0; ks < 2; ++ks)
                vf[ni][ks] = *(const uint4*)(Vs + (ni * 16 + fr) * 72 + ks * 32 + fg * 8);
#pragma unroll
        for (int mi = 0; mi < 2; ++mi) {
            uint4 pf0 = *(const uint4*)(pw + (mi * 16 + fr) * 72 + fg * 8);
            uint4 pf1 = *(const uint4*)(pw + (mi * 16 + fr) * 72 + 32 + fg * 8);
#pragma unroll
            for (int ni = 0; ni < 4; ++ni) {
                oacc[mi][ni] = mfma16(pf0, vf[ni][0], oacc[mi][ni]);
                oacc[mi][ni] = mfma16(pf1, vf[ni][1], oacc[mi][ni]);
            }
        }
        __syncthreads();
    }

    // normalize + store
#pragma unroll
    for (int mi = 0; mi < 2; ++mi) {
        float inv[4];
#pragma unroll
        for (int r = 0; r < 4; ++r) inv[r] = 1.0f / lst[mi][r];
#pragma unroll
        for (int r = 0; r < 4; ++r) {
            int t = q0 + wv * 32 + mi * 16 + fg * 4 + r;
            size_t base = ((size_t)(b * TT + t)) * CC + h * 64 + fr;
#pragma unroll
            for (int ni = 0; ni < 4; ++ni)
                Att[base + ni * 16] = f2b(oacc[mi][ni][r] * inv[r]);
        }
    }
}

extern "C" void kernel_launch(void* const* d_in, const int* in_sizes, int n_in,
                              void* d_out, int out_size, void* d_ws, size_t ws_size,
                              hipStream_t stream) {
    (void)in_sizes; (void)n_in; (void)out_size; (void)ws_size;
    const float* v  = (const float*)d_in[0];
    const float* k  = (const float*)d_in[1];
    const float* q  = (const float*)d_in[2];
    // d_in[3] = mask (tril by construction; applied analytically)
    const float* Wk = (const float*)d_in[4];
    const float* Wq = (const float*)d_in[5];
    const float* Wv = (const float*)d_in[6];
    const float* Wo = (const float*)d_in[7];
    const float* bo = (const float*)d_in[8];

    char* ws = (char*)d_ws;
    const size_t SI = (size_t)MM * CC * 2;   // 16.78 MB
    const size_t SW = (size_t)CC * CC * 2;   // 2.1 MB
    u16* qb  = (u16*)(ws + 0 * SI);
    u16* kb  = (u16*)(ws + 1 * SI);
    u16* vb  = (u16*)(ws + 2 * SI);
    u16* Qp  = (u16*)(ws + 3 * SI);
    u16* Kp  = (u16*)(ws + 4 * SI);
    u16* Vtp = (u16*)(ws + 5 * SI);
    u16* wq  = (u16*)(ws + 6 * SI + 0 * SW);
    u16* wk  = (u16*)(ws + 6 * SI + 1 * SW);
    u16* wvv = (u16*)(ws + 6 * SI + 2 * SW);
    u16* wo  = (u16*)(ws + 6 * SI + 3 * SW);
    u16* att = qb;  // alias: q bf16 copy is dead after Q projection

    const int nin = MM * CC;   // 8388608
    const int nw  = CC * CC;   // 1048576
    cvt_kernel<<<nin / 1024, 256, 0, stream>>>(q, qb, nin);
    cvt_kernel<<<nin / 1024, 256, 0, stream>>>(k, kb, nin);
    cvt_kernel<<<nin / 1024, 256, 0, stream>>>(v, vb, nin);
    cvt_kernel<<<nw / 1024, 256, 0, stream>>>(Wq, wq, nw);
    cvt_kernel<<<nw / 1024, 256, 0, stream>>>(Wk, wk, nw);
    cvt_kernel<<<nw / 1024, 256, 0, stream>>>(Wv, wvv, nw);
    cvt_kernel<<<nw / 1024, 256, 0, stream>>>(Wo, wo, nw);

    dim3 gg(MM / 128, CC / 128);
    gemm_bt<0><<<gg, 256, 0, stream>>>(qb, wq, nullptr, Qp);
    gemm_bt<0><<<gg, 256, 0, stream>>>(kb, wk, nullptr, Kp);
    gemm_bt<1><<<gg, 256, 0, stream>>>(vb, wvv, nullptr, Vtp);
    flash_attn<<<dim3(16, 64), 256, 0, stream>>>(Qp, Kp, Vtp, att);
    gemm_bt<2><<<gg, 256, 0, stream>>>(att, wo, bo, d_out);
}

// Round 4
// 343.507 us; speedup vs baseline: 1.5513x; 1.5513x over previous
//
#include <hip/hip_runtime.h>
#include <stdint.h>

#define BB 4
#define TT 2048
#define CC 1024
#define HH 16
#define DD 64
#define MM (BB*TT)

typedef unsigned short u16;
typedef unsigned int   u32;
typedef __attribute__((ext_vector_type(8))) __bf16 bf16x8;
typedef __attribute__((ext_vector_type(4))) float  f32x4;

typedef __attribute__((address_space(1))) const u32 as1_u32;
typedef __attribute__((address_space(3))) u32       as3_u32;

// f32 -> bf16 round-to-nearest-even
__device__ __forceinline__ u16 f2b(float f) {
    u32 u = __builtin_bit_cast(u32, f);
    u32 r = u + 0x7FFFu + ((u >> 16) & 1u);
    return (u16)(r >> 16);
}

__device__ __forceinline__ f32x4 mfma16(uint4 a, uint4 b, f32x4 c) {
    return __builtin_amdgcn_mfma_f32_16x16x32_bf16(
        __builtin_bit_cast(bf16x8, a), __builtin_bit_cast(bf16x8, b), c, 0, 0, 0);
}

__device__ __forceinline__ void glds16(const u16* g, u16* l) {
    __builtin_amdgcn_global_load_lds((const as1_u32*)g, (as3_u32*)l, 16, 0, 0);
}

// ---------------- f32 -> bf16 convert ----------------
__global__ __launch_bounds__(256) void cvt_kernel(const float* __restrict__ s,
                                                  u16* __restrict__ d, int n) {
    int i = (blockIdx.x * 256 + threadIdx.x) * 4;
    if (i < n) {
        float4 v = *(const float4*)(s + i);
        ushort4 o;
        o.x = f2b(v.x); o.y = f2b(v.y); o.z = f2b(v.z); o.w = f2b(v.w);
        *(ushort4*)(d + i) = o;
    }
}

// ---------------- GEMM: Out[m,n] = sum_k A[m,k]*Bw[n,k]  (both K-contiguous bf16) ----
// MODE 0: bf16 row-major [M,N] out, scaled
// MODE 1: bf16 per-head transposed out with k-permuted layout:
//         Out[((b*H+h)*64+d)*T + perm(t)], perm within 64-block: p=(t&15)*4+(t>>4)
// MODE 2: f32 out + bias
template<int MODE>
__global__ __launch_bounds__(256, 2)
void gemm_bt(const u16* __restrict__ A, const u16* __restrict__ Bw,
             const float* __restrict__ bias, void* __restrict__ Out, float scale) {
    __shared__ u16 As[128 * 32];
    __shared__ u16 Bs[128 * 32];

    const int tid  = threadIdx.x;
    const int lane = tid & 63;
    const int wv   = tid >> 6;
    const int m0   = blockIdx.x * 128;
    const int n0   = blockIdx.y * 128;
    const int wm   = (wv & 1) * 64;
    const int wn   = (wv >> 1) * 64;
    const int fr   = lane & 15;
    const int fg   = lane >> 4;

    const int srow = wv * 16 + (lane >> 2);
    const int sel  = (lane & 3) * 8;

    const u16* gA0 = A  + (size_t)(m0 + srow) * CC + sel;
    const u16* gA1 = gA0 + (size_t)64 * CC;
    const u16* gB0 = Bw + (size_t)(n0 + srow) * CC + sel;
    const u16* gB1 = gB0 + (size_t)64 * CC;
    u16* sA0 = As + wv * 512;
    u16* sA1 = As + 2048 + wv * 512;
    u16* sB0 = Bs + wv * 512;
    u16* sB1 = Bs + 2048 + wv * 512;

    f32x4 acc[4][4] = {};

    for (int k0 = 0; k0 < CC; k0 += 32) {
        glds16(gA0 + k0, sA0);
        glds16(gA1 + k0, sA1);
        glds16(gB0 + k0, sB0);
        glds16(gB1 + k0, sB1);
        __syncthreads();
        uint4 af[4], bfr[4];
#pragma unroll
        for (int i = 0; i < 4; ++i)
            af[i] = *(const uint4*)(As + (wm + i * 16 + fr) * 32 + fg * 8);
#pragma unroll
        for (int i = 0; i < 4; ++i)
            bfr[i] = *(const uint4*)(Bs + (wn + i * 16 + fr) * 32 + fg * 8);
#pragma unroll
        for (int mi = 0; mi < 4; ++mi)
#pragma unroll
            for (int ni = 0; ni < 4; ++ni)
                acc[mi][ni] = mfma16(af[mi], bfr[ni], acc[mi][ni]);
        __syncthreads();
    }

    if constexpr (MODE == 0) {
        u16* O = (u16*)Out;
#pragma unroll
        for (int mi = 0; mi < 4; ++mi)
#pragma unroll
            for (int r = 0; r < 4; ++r) {
                int m = m0 + wm + mi * 16 + fg * 4 + r;
                size_t base = (size_t)m * CC + n0 + wn + fr;
#pragma unroll
                for (int ni = 0; ni < 4; ++ni)
                    O[base + ni * 16] = f2b(acc[mi][ni][r] * scale);
            }
    } else if constexpr (MODE == 1) {
        u16* O = (u16*)Out;
#pragma unroll
        for (int mi = 0; mi < 4; ++mi) {
            int m  = m0 + wm + mi * 16 + fg * 4;   // 4 consecutive t, aligned 4
            int b_ = m >> 11;
            int t0 = m & 2047;
            int blk = t0 >> 6;
            int tl  = t0 & 63;                      // in {0,4,...,60}
            int pbase = (blk << 6) + ((tl & 15) << 2) + (tl >> 4);
#pragma unroll
            for (int ni = 0; ni < 4; ++ni) {
                int n = n0 + wn + ni * 16 + fr;     // = h*64 + d
                u16* orow = O + ((size_t)b_ * CC + n) * TT;
#pragma unroll
                for (int r = 0; r < 4; ++r)
                    orow[pbase + 4 * r] = f2b(acc[mi][ni][r] * scale);
            }
        }
    } else {
        float* O = (float*)Out;
#pragma unroll
        for (int mi = 0; mi < 4; ++mi)
#pragma unroll
            for (int r = 0; r < 4; ++r) {
                int m = m0 + wm + mi * 16 + fg * 4 + r;
                size_t base = (size_t)m * CC + n0 + wn + fr;
#pragma unroll
                for (int ni = 0; ni < 4; ++ni)
                    O[base + ni * 16] = acc[mi][ni][r] + bias[n0 + wn + ni * 16 + fr];
            }
    }
}

// ---------------- flash attention (fixed-max, MFMA row-sums, balanced pairing) ------
// Qp (pre-scaled by 0.5*log2e), Kp: bf16 [B,T,C]; Vt: bf16 [B*H*64, T] k-permuted;
// Att out: bf16 [B,T,C]
__global__ __launch_bounds__(256, 2)
void flash_attn(const u16* __restrict__ Qp, const u16* __restrict__ Kp,
                const u16* __restrict__ Vt, u16* __restrict__ Att) {
    __shared__ u16 Qs[128 * 72];
    __shared__ u16 Ks[64 * 72];
    __shared__ u16 Vs[64 * 72];
    __shared__ u16 Ps[4 * 32 * 72];

    const int tid = threadIdx.x, lane = tid & 63, wv = tid >> 6;
    const int fr = lane & 15, fg = lane >> 4;
    const int bh = blockIdx.y;
    const int b = bh >> 4, h = bh & 15;
    u16* pw = Ps + wv * 32 * 72;
    const uint4 ONES = {0x3F803F80u, 0x3F803F80u, 0x3F803F80u, 0x3F803F80u};

    for (int half = 0; half < 2; ++half) {
        const int qi = half ? (15 - (int)blockIdx.x) : (int)blockIdx.x;
        const int q0 = qi * 128;

        // stage Q tile [128][64] -> Qs[128][72]
#pragma unroll
        for (int i = 0; i < 4; ++i) {
            int ch = i * 256 + tid;
            int r = ch >> 3, cp = (ch & 7) * 8;
            *(uint4*)(Qs + r * 72 + cp) =
                *(const uint4*)(Qp + ((size_t)(b * TT + q0 + r)) * CC + h * 64 + cp);
        }
        __syncthreads();

        uint4 qf[2][2];
#pragma unroll
        for (int mi = 0; mi < 2; ++mi)
#pragma unroll
            for (int ks = 0; ks < 2; ++ks)
                qf[mi][ks] = *(const uint4*)(Qs + (wv * 32 + mi * 16 + fr) * 72 + ks * 32 + fg * 8);

        f32x4 oacc[2][4] = {};
        f32x4 lacc[2] = {};

        const int nkt = 2 * (qi + 1);
        for (int kt = 0; kt < nkt; ++kt) {
            const int k0 = kt * 64;
            // stage K tile [64][64] and permuted-V^T tile [64 d][64 p]
#pragma unroll
            for (int i = 0; i < 2; ++i) {
                int ch = i * 256 + tid;
                int r = ch >> 3, cp = (ch & 7) * 8;
                *(uint4*)(Ks + r * 72 + cp) =
                    *(const uint4*)(Kp + ((size_t)(b * TT + k0 + r)) * CC + h * 64 + cp);
                *(uint4*)(Vs + r * 72 + cp) =
                    *(const uint4*)(Vt + ((size_t)(bh * 64 + r)) * TT + k0 + cp);
            }
            __syncthreads();

            // S = Q K^T  (per wave: 32 q-rows x 64 k-cols); Q already scaled to exp2 domain
            uint4 kf[4][2];
#pragma unroll
            for (int ni = 0; ni < 4; ++ni)
#pragma unroll
                for (int ks = 0; ks < 2; ++ks)
                    kf[ni][ks] = *(const uint4*)(Ks + (ni * 16 + fr) * 72 + ks * 32 + fg * 8);
            f32x4 s[2][4];
#pragma unroll
            for (int mi = 0; mi < 2; ++mi)
#pragma unroll
                for (int ni = 0; ni < 4; ++ni) {
                    f32x4 a = {0.f, 0.f, 0.f, 0.f};
                    a = mfma16(qf[mi][0], kf[ni][0], a);
                    a = mfma16(qf[mi][1], kf[ni][1], a);
                    s[mi][ni] = a;
                }

            // causal mask (true-t coords), only where the tile touches the diagonal
            if (k0 + 63 > q0 + wv * 32) {
#pragma unroll
                for (int mi = 0; mi < 2; ++mi)
#pragma unroll
                    for (int r = 0; r < 4; ++r) {
                        int tq = q0 + wv * 32 + mi * 16 + fg * 4 + r;
#pragma unroll
                        for (int ni = 0; ni < 4; ++ni) {
                            int tk = k0 + ni * 16 + fr;
                            if (tk > tq) s[mi][ni][r] = -1e30f;
                        }
                    }
            }

            // p = exp2(s); pack 4 bf16 (k-permuted contiguous) -> one b64 LDS write
#pragma unroll
            for (int mi = 0; mi < 2; ++mi)
#pragma unroll
                for (int r = 0; r < 4; ++r) {
                    float p0 = __builtin_amdgcn_exp2f(s[mi][0][r]);
                    float p1 = __builtin_amdgcn_exp2f(s[mi][1][r]);
                    float p2 = __builtin_amdgcn_exp2f(s[mi][2][r]);
                    float p3 = __builtin_amdgcn_exp2f(s[mi][3][r]);
                    u32 d0 = (u32)f2b(p0) | ((u32)f2b(p1) << 16);
                    u32 d1 = (u32)f2b(p2) | ((u32)f2b(p3) << 16);
                    uint2 dd = {d0, d1};
                    *(uint2*)(pw + (mi * 16 + fg * 4 + r) * 72 + fr * 4) = dd;
                }

            // O += P V ; l += P * ones   (both in MFMA)
            uint4 vf[4][2];
#pragma unroll
            for (int ni = 0; ni < 4; ++ni)
#pragma unroll
                for (int ks = 0; ks < 2; ++ks)
                    vf[ni][ks] = *(const uint4*)(Vs + (ni * 16 + fr) * 72 + ks * 32 + fg * 8);
#pragma unroll
            for (int mi = 0; mi < 2; ++mi) {
                uint4 pf0 = *(const uint4*)(pw + (mi * 16 + fr) * 72 + fg * 8);
                uint4 pf1 = *(const uint4*)(pw + (mi * 16 + fr) * 72 + 32 + fg * 8);
                lacc[mi] = mfma16(pf0, ONES, lacc[mi]);
                lacc[mi] = mfma16(pf1, ONES, lacc[mi]);
#pragma unroll
                for (int ni = 0; ni < 4; ++ni) {
                    oacc[mi][ni] = mfma16(pf0, vf[ni][0], oacc[mi][ni]);
                    oacc[mi][ni] = mfma16(pf1, vf[ni][1], oacc[mi][ni]);
                }
            }
            __syncthreads();
        }

        // normalize + store
#pragma unroll
        for (int mi = 0; mi < 2; ++mi)
#pragma unroll
            for (int r = 0; r < 4; ++r) {
                float inv = 1.0f / lacc[mi][r];
                int t = q0 + wv * 32 + mi * 16 + fg * 4 + r;
                size_t base = ((size_t)(b * TT + t)) * CC + h * 64 + fr;
#pragma unroll
                for (int ni = 0; ni < 4; ++ni)
                    Att[base + ni * 16] = f2b(oacc[mi][ni][r] * inv);
            }
    }
}

extern "C" void kernel_launch(void* const* d_in, const int* in_sizes, int n_in,
                              void* d_out, int out_size, void* d_ws, size_t ws_size,
                              hipStream_t stream) {
    (void)in_sizes; (void)n_in; (void)out_size; (void)ws_size;
    const float* v  = (const float*)d_in[0];
    const float* k  = (const float*)d_in[1];
    const float* q  = (const float*)d_in[2];
    // d_in[3] = mask (tril by construction; applied analytically)
    const float* Wk = (const float*)d_in[4];
    const float* Wq = (const float*)d_in[5];
    const float* Wv = (const float*)d_in[6];
    const float* Wo = (const float*)d_in[7];
    const float* bo = (const float*)d_in[8];

    char* ws = (char*)d_ws;
    const size_t SI = (size_t)MM * CC * 2;   // 16.78 MB
    const size_t SW = (size_t)CC * CC * 2;   // 2.1 MB
    u16* qb  = (u16*)(ws + 0 * SI);
    u16* kb  = (u16*)(ws + 1 * SI);
    u16* vb  = (u16*)(ws + 2 * SI);
    u16* Qp  = (u16*)(ws + 3 * SI);
    u16* Kp  = (u16*)(ws + 4 * SI);
    u16* Vtp = (u16*)(ws + 5 * SI);
    u16* wq  = (u16*)(ws + 6 * SI + 0 * SW);
    u16* wk  = (u16*)(ws + 6 * SI + 1 * SW);
    u16* wvv = (u16*)(ws + 6 * SI + 2 * SW);
    u16* wo  = (u16*)(ws + 6 * SI + 3 * SW);
    u16* att = qb;  // alias: q bf16 copy is dead after Q projection

    const int nin = MM * CC;   // 8388608
    const int nw  = CC * CC;   // 1048576
    cvt_kernel<<<nin / 1024, 256, 0, stream>>>(q, qb, nin);
    cvt_kernel<<<nin / 1024, 256, 0, stream>>>(k, kb, nin);
    cvt_kernel<<<nin / 1024, 256, 0, stream>>>(v, vb, nin);
    cvt_kernel<<<nw / 1024, 256, 0, stream>>>(Wq, wq, nw);
    cvt_kernel<<<nw / 1024, 256, 0, stream>>>(Wk, wk, nw);
    cvt_kernel<<<nw / 1024, 256, 0, stream>>>(Wv, wvv, nw);
    cvt_kernel<<<nw / 1024, 256, 0, stream>>>(Wo, wo, nw);

    const float csc = 0.5f * 1.44269504088896f;  // (1/sqrt(B)) * log2(e)
    dim3 gg(MM / 128, CC / 128);
    gemm_bt<0><<<gg, 256, 0, stream>>>(qb, wq, nullptr, Qp, csc);
    gemm_bt<0><<<gg, 256, 0, stream>>>(kb, wk, nullptr, Kp, 1.0f);
    gemm_bt<1><<<gg, 256, 0, stream>>>(vb, wvv, nullptr, Vtp, 1.0f);
    flash_attn<<<dim3(8, 64), 256, 0, stream>>>(Qp, Kp, Vtp, att);
    gemm_bt<2><<<gg, 256, 0, stream>>>(att, wo, bo, d_out, 1.0f);
}

// Round 5
// 315.322 us; speedup vs baseline: 1.6899x; 1.0894x over previous
//
#include <hip/hip_runtime.h>
#include <stdint.h>

#define BB 4
#define TT 2048
#define CC 1024
#define HH 16
#define DD 64
#define MM (BB*TT)

typedef unsigned short u16;
typedef unsigned int   u32;
typedef __attribute__((ext_vector_type(8))) __bf16 bf16x8;
typedef __attribute__((ext_vector_type(4))) float  f32x4;

typedef __attribute__((address_space(1))) const u32 as1_u32;
typedef __attribute__((address_space(3))) u32       as3_u32;

// f32 -> bf16 round-to-nearest-even
__device__ __forceinline__ u16 f2b(float f) {
    u32 u = __builtin_bit_cast(u32, f);
    u32 r = u + 0x7FFFu + ((u >> 16) & 1u);
    return (u16)(r >> 16);
}

__device__ __forceinline__ f32x4 mfma16(uint4 a, uint4 b, f32x4 c) {
    return __builtin_amdgcn_mfma_f32_16x16x32_bf16(
        __builtin_bit_cast(bf16x8, a), __builtin_bit_cast(bf16x8, b), c, 0, 0, 0);
}

__device__ __forceinline__ void glds16(const u16* g, u16* l) {
    __builtin_amdgcn_global_load_lds((const as1_u32*)g, (as3_u32*)l, 16, 0, 0);
}

// ---------------- f32 -> bf16 converts (fused multi-tensor) ----------------
__global__ __launch_bounds__(256) void cvt3_kernel(const float* __restrict__ s0,
                                                   const float* __restrict__ s1,
                                                   const float* __restrict__ s2,
                                                   u16* __restrict__ d0,
                                                   u16* __restrict__ d1,
                                                   u16* __restrict__ d2, int n) {
    const float* s; u16* d;
    if (blockIdx.y == 0)      { s = s0; d = d0; }
    else if (blockIdx.y == 1) { s = s1; d = d1; }
    else                      { s = s2; d = d2; }
    int i = (blockIdx.x * 256 + threadIdx.x) * 4;
    if (i < n) {
        float4 v = *(const float4*)(s + i);
        ushort4 o;
        o.x = f2b(v.x); o.y = f2b(v.y); o.z = f2b(v.z); o.w = f2b(v.w);
        *(ushort4*)(d + i) = o;
    }
}

__global__ __launch_bounds__(256) void cvt4_kernel(const float* __restrict__ s0,
                                                   const float* __restrict__ s1,
                                                   const float* __restrict__ s2,
                                                   const float* __restrict__ s3,
                                                   u16* __restrict__ d0,
                                                   u16* __restrict__ d1,
                                                   u16* __restrict__ d2,
                                                   u16* __restrict__ d3, int n) {
    const float* s; u16* d;
    if (blockIdx.y == 0)      { s = s0; d = d0; }
    else if (blockIdx.y == 1) { s = s1; d = d1; }
    else if (blockIdx.y == 2) { s = s2; d = d2; }
    else                      { s = s3; d = d3; }
    int i = (blockIdx.x * 256 + threadIdx.x) * 4;
    if (i < n) {
        float4 v = *(const float4*)(s + i);
        ushort4 o;
        o.x = f2b(v.x); o.y = f2b(v.y); o.z = f2b(v.z); o.w = f2b(v.w);
        *(ushort4*)(d + i) = o;
    }
}

// ---------------- GEMM: Out[m,n] = sum_k A[m,k]*Bw[n,k]  (both K-contiguous bf16) ----
// BK=64, single-buffered, XOR-swizzled LDS chunks (swizzle applied on the global
// gather side since global_load_lds fixes the LDS mapping to uniform+lane*16B).
// MODE 0: bf16 row-major [M,N] out, scaled
// MODE 1: bf16 per-head transposed out with k-permuted layout:
//         Out[((b*H+h)*64+d)*T + perm(t)], perm within 64-block: p=(t&15)*4+(t>>4)
// MODE 2: f32 out + bias
template<int MODE>
__global__ __launch_bounds__(256, 2)
void gemm_bt(const u16* __restrict__ A, const u16* __restrict__ Bw,
             const float* __restrict__ bias, void* __restrict__ Out, float scale) {
    __shared__ u16 As[128 * 64];
    __shared__ u16 Bs[128 * 64];

    const int tid  = threadIdx.x;
    const int lane = tid & 63;
    const int wv   = tid >> 6;
    const int m0   = blockIdx.x * 128;
    const int n0   = blockIdx.y * 128;
    const int wm   = (wv & 1) * 64;
    const int wn   = (wv >> 1) * 64;
    const int fr   = lane & 15;
    const int fg   = lane >> 4;
    const int xsw  = fr & 7;             // per-lane row-phase for read-side deswizzle

    // staging: wave wv covers rows [wv*32, wv*32+32), 4 glds16 per operand.
    // lane l -> row +(l>>3), LDS chunk (l&7); fetch global chunk (l&7)^(row&7).
    const int lrow = lane >> 3;                               // 0..7
    const int lcol = (((lane & 7) ^ lrow) * 8);               // swizzled source chunk
    const u16* gA = A  + (size_t)(m0 + wv * 32 + lrow) * CC + lcol;
    const u16* gB = Bw + (size_t)(n0 + wv * 32 + lrow) * CC + lcol;
    u16* sA = As + (wv * 32) * 64;
    u16* sB = Bs + (wv * 32) * 64;

    f32x4 acc[4][4] = {};

    for (int k0 = 0; k0 < CC; k0 += 64) {
        __syncthreads();                 // prev-iter LDS reads complete
#pragma unroll
        for (int j = 0; j < 4; ++j) {
            glds16(gA + (size_t)j * 8 * CC + k0, sA + j * 512);
            glds16(gB + (size_t)j * 8 * CC + k0, sB + j * 512);
        }
        __syncthreads();                 // staging complete
#pragma unroll
        for (int ks = 0; ks < 2; ++ks) {
            uint4 af[4], bfr[4];
#pragma unroll
            for (int i = 0; i < 4; ++i) {
                int ca = ((ks * 4 + fg) ^ xsw) * 8;
                af[i]  = *(const uint4*)(As + (wm + i * 16 + fr) * 64 + ca);
                bfr[i] = *(const uint4*)(Bs + (wn + i * 16 + fr) * 64 + ca);
            }
#pragma unroll
            for (int mi = 0; mi < 4; ++mi)
#pragma unroll
                for (int ni = 0; ni < 4; ++ni)
                    acc[mi][ni] = mfma16(af[mi], bfr[ni], acc[mi][ni]);
        }
    }

    if constexpr (MODE == 0) {
        u16* O = (u16*)Out;
#pragma unroll
        for (int mi = 0; mi < 4; ++mi)
#pragma unroll
            for (int r = 0; r < 4; ++r) {
                int m = m0 + wm + mi * 16 + fg * 4 + r;
                size_t base = (size_t)m * CC + n0 + wn + fr;
#pragma unroll
                for (int ni = 0; ni < 4; ++ni)
                    O[base + ni * 16] = f2b(acc[mi][ni][r] * scale);
            }
    } else if constexpr (MODE == 1) {
        u16* O = (u16*)Out;
#pragma unroll
        for (int mi = 0; mi < 4; ++mi) {
            int m  = m0 + wm + mi * 16 + fg * 4;   // 4 consecutive t, aligned 4
            int b_ = m >> 11;
            int t0 = m & 2047;
            int blk = t0 >> 6;
            int tl  = t0 & 63;                      // in {0,4,...,60}
            int pbase = (blk << 6) + ((tl & 15) << 2) + (tl >> 4);
#pragma unroll
            for (int ni = 0; ni < 4; ++ni) {
                int n = n0 + wn + ni * 16 + fr;     // = h*64 + d
                u16* orow = O + ((size_t)b_ * CC + n) * TT;
#pragma unroll
                for (int r = 0; r < 4; ++r)
                    orow[pbase + 4 * r] = f2b(acc[mi][ni][r] * scale);
            }
        }
    } else {
        float* O = (float*)Out;
#pragma unroll
        for (int mi = 0; mi < 4; ++mi)
#pragma unroll
            for (int r = 0; r < 4; ++r) {
                int m = m0 + wm + mi * 16 + fg * 4 + r;
                size_t base = (size_t)m * CC + n0 + wn + fr;
#pragma unroll
                for (int ni = 0; ni < 4; ++ni)
                    O[base + ni * 16] = acc[mi][ni][r] + bias[n0 + wn + ni * 16 + fr];
            }
    }
}

// ---------------- flash attention (fixed-max, MFMA row-sums, balanced pairing) ------
// Qp (pre-scaled by 0.5*log2e), Kp: bf16 [B,T,C]; Vt: bf16 [B*H*64, T] k-permuted;
// Att out: bf16 [B,T,C]
__global__ __launch_bounds__(256, 2)
void flash_attn(const u16* __restrict__ Qp, const u16* __restrict__ Kp,
                const u16* __restrict__ Vt, u16* __restrict__ Att) {
    __shared__ u16 Qs[128 * 72];
    __shared__ u16 Ks[64 * 72];
    __shared__ u16 Vs[64 * 72];
    __shared__ u16 Ps[4 * 32 * 72];

    const int tid = threadIdx.x, lane = tid & 63, wv = tid >> 6;
    const int fr = lane & 15, fg = lane >> 4;
    const int bh = blockIdx.y;
    const int b = bh >> 4, h = bh & 15;
    u16* pw = Ps + wv * 32 * 72;
    const uint4 ONES = {0x3F803F80u, 0x3F803F80u, 0x3F803F80u, 0x3F803F80u};

    for (int half = 0; half < 2; ++half) {
        const int qi = half ? (15 - (int)blockIdx.x) : (int)blockIdx.x;
        const int q0 = qi * 128;

        // stage Q tile [128][64] -> Qs[128][72]
#pragma unroll
        for (int i = 0; i < 4; ++i) {
            int ch = i * 256 + tid;
            int r = ch >> 3, cp = (ch & 7) * 8;
            *(uint4*)(Qs + r * 72 + cp) =
                *(const uint4*)(Qp + ((size_t)(b * TT + q0 + r)) * CC + h * 64 + cp);
        }
        __syncthreads();

        uint4 qf[2][2];
#pragma unroll
        for (int mi = 0; mi < 2; ++mi)
#pragma unroll
            for (int ks = 0; ks < 2; ++ks)
                qf[mi][ks] = *(const uint4*)(Qs + (wv * 32 + mi * 16 + fr) * 72 + ks * 32 + fg * 8);

        f32x4 oacc[2][4] = {};
        f32x4 lacc[2] = {};

        const int nkt = 2 * (qi + 1);
        for (int kt = 0; kt < nkt; ++kt) {
            const int k0 = kt * 64;
            // stage K tile [64][64] and permuted-V^T tile [64 d][64 p]
#pragma unroll
            for (int i = 0; i < 2; ++i) {
                int ch = i * 256 + tid;
                int r = ch >> 3, cp = (ch & 7) * 8;
                *(uint4*)(Ks + r * 72 + cp) =
                    *(const uint4*)(Kp + ((size_t)(b * TT + k0 + r)) * CC + h * 64 + cp);
                *(uint4*)(Vs + r * 72 + cp) =
                    *(const uint4*)(Vt + ((size_t)(bh * 64 + r)) * TT + k0 + cp);
            }
            __syncthreads();

            // S = Q K^T  (per wave: 32 q-rows x 64 k-cols); Q already scaled to exp2 domain
            uint4 kf[4][2];
#pragma unroll
            for (int ni = 0; ni < 4; ++ni)
#pragma unroll
                for (int ks = 0; ks < 2; ++ks)
                    kf[ni][ks] = *(const uint4*)(Ks + (ni * 16 + fr) * 72 + ks * 32 + fg * 8);
            f32x4 s[2][4];
#pragma unroll
            for (int mi = 0; mi < 2; ++mi)
#pragma unroll
                for (int ni = 0; ni < 4; ++ni) {
                    f32x4 a = {0.f, 0.f, 0.f, 0.f};
                    a = mfma16(qf[mi][0], kf[ni][0], a);
                    a = mfma16(qf[mi][1], kf[ni][1], a);
                    s[mi][ni] = a;
                }

            // causal mask (true-t coords), only where the tile touches the diagonal
            if (k0 + 63 > q0 + wv * 32) {
#pragma unroll
                for (int mi = 0; mi < 2; ++mi)
#pragma unroll
                    for (int r = 0; r < 4; ++r) {
                        int tq = q0 + wv * 32 + mi * 16 + fg * 4 + r;
#pragma unroll
                        for (int ni = 0; ni < 4; ++ni) {
                            int tk = k0 + ni * 16 + fr;
                            if (tk > tq) s[mi][ni][r] = -1e30f;
                        }
                    }
            }

            // p = exp2(s); pack 4 bf16 (k-permuted contiguous) -> one b64 LDS write
#pragma unroll
            for (int mi = 0; mi < 2; ++mi)
#pragma unroll
                for (int r = 0; r < 4; ++r) {
                    float p0 = __builtin_amdgcn_exp2f(s[mi][0][r]);
                    float p1 = __builtin_amdgcn_exp2f(s[mi][1][r]);
                    float p2 = __builtin_amdgcn_exp2f(s[mi][2][r]);
                    float p3 = __builtin_amdgcn_exp2f(s[mi][3][r]);
                    u32 d0 = (u32)f2b(p0) | ((u32)f2b(p1) << 16);
                    u32 d1 = (u32)f2b(p2) | ((u32)f2b(p3) << 16);
                    uint2 dd = {d0, d1};
                    *(uint2*)(pw + (mi * 16 + fg * 4 + r) * 72 + fr * 4) = dd;
                }

            // O += P V ; l += P * ones   (both in MFMA)
            uint4 vf[4][2];
#pragma unroll
            for (int ni = 0; ni < 4; ++ni)
#pragma unroll
                for (int ks = 0; ks < 2; ++ks)
                    vf[ni][ks] = *(const uint4*)(Vs + (ni * 16 + fr) * 72 + ks * 32 + fg * 8);
#pragma unroll
            for (int mi = 0; mi < 2; ++mi) {
                uint4 pf0 = *(const uint4*)(pw + (mi * 16 + fr) * 72 + fg * 8);
                uint4 pf1 = *(const uint4*)(pw + (mi * 16 + fr) * 72 + 32 + fg * 8);
                lacc[mi] = mfma16(pf0, ONES, lacc[mi]);
                lacc[mi] = mfma16(pf1, ONES, lacc[mi]);
#pragma unroll
                for (int ni = 0; ni < 4; ++ni) {
                    oacc[mi][ni] = mfma16(pf0, vf[ni][0], oacc[mi][ni]);
                    oacc[mi][ni] = mfma16(pf1, vf[ni][1], oacc[mi][ni]);
                }
            }
            __syncthreads();
        }

        // normalize + store
#pragma unroll
        for (int mi = 0; mi < 2; ++mi)
#pragma unroll
            for (int r = 0; r < 4; ++r) {
                float inv = 1.0f / lacc[mi][r];
                int t = q0 + wv * 32 + mi * 16 + fg * 4 + r;
                size_t base = ((size_t)(b * TT + t)) * CC + h * 64 + fr;
#pragma unroll
                for (int ni = 0; ni < 4; ++ni)
                    Att[base + ni * 16] = f2b(oacc[mi][ni][r] * inv);
            }
    }
}

extern "C" void kernel_launch(void* const* d_in, const int* in_sizes, int n_in,
                              void* d_out, int out_size, void* d_ws, size_t ws_size,
                              hipStream_t stream) {
    (void)in_sizes; (void)n_in; (void)out_size; (void)ws_size;
    const float* v  = (const float*)d_in[0];
    const float* k  = (const float*)d_in[1];
    const float* q  = (const float*)d_in[2];
    // d_in[3] = mask (tril by construction; applied analytically)
    const float* Wk = (const float*)d_in[4];
    const float* Wq = (const float*)d_in[5];
    const float* Wv = (const float*)d_in[6];
    const float* Wo = (const float*)d_in[7];
    const float* bo = (const float*)d_in[8];

    char* ws = (char*)d_ws;
    const size_t SI = (size_t)MM * CC * 2;   // 16.78 MB
    const size_t SW = (size_t)CC * CC * 2;   // 2.1 MB
    u16* qb  = (u16*)(ws + 0 * SI);
    u16* kb  = (u16*)(ws + 1 * SI);
    u16* vb  = (u16*)(ws + 2 * SI);
    u16* Qp  = (u16*)(ws + 3 * SI);
    u16* Kp  = (u16*)(ws + 4 * SI);
    u16* Vtp = (u16*)(ws + 5 * SI);
    u16* wq  = (u16*)(ws + 6 * SI + 0 * SW);
    u16* wk  = (u16*)(ws + 6 * SI + 1 * SW);
    u16* wvv = (u16*)(ws + 6 * SI + 2 * SW);
    u16* wo  = (u16*)(ws + 6 * SI + 3 * SW);
    u16* att = qb;  // alias: q bf16 copy is dead after Q projection

    const int nin = MM * CC;   // 8388608
    const int nw  = CC * CC;   // 1048576
    cvt3_kernel<<<dim3(nin / 1024, 3), 256, 0, stream>>>(q, k, v, qb, kb, vb, nin);
    cvt4_kernel<<<dim3(nw / 1024, 4), 256, 0, stream>>>(Wq, Wk, Wv, Wo, wq, wk, wvv, wo, nw);

    const float csc = 0.5f * 1.44269504088896f;  // (1/sqrt(B)) * log2(e)
    dim3 gg(MM / 128, CC / 128);
    gemm_bt<0><<<gg, 256, 0, stream>>>(qb, wq, nullptr, Qp, csc);
    gemm_bt<0><<<gg, 256, 0, stream>>>(kb, wk, nullptr, Kp, 1.0f);
    gemm_bt<1><<<gg, 256, 0, stream>>>(vb, wvv, nullptr, Vtp, 1.0f);
    flash_attn<<<dim3(8, 64), 256, 0, stream>>>(Qp, Kp, Vtp, att);
    gemm_bt<2><<<gg, 256, 0, stream>>>(att, wo, bo, d_out, 1.0f);
}